// Round 1
// baseline (349.270 us; speedup 1.0000x reference)
//
#include <hip/hip_runtime.h>
#include <hip/hip_bf16.h>
#include <stdint.h>

// Problem constants: B=2, S=2048, D=1024, H=16, HD=64
#define NB 2
#define NS 2048
#define ND 1024
#define NH 16
#define NHD 64
#define NM (NB*NS)   // 4096 rows in the projection GEMMs

typedef __attribute__((ext_vector_type(8))) short bf16x8;
typedef __attribute__((ext_vector_type(4))) float f32x4;

static __device__ __forceinline__ f32x4 mfma16(bf16x8 a, bf16x8 b, f32x4 c) {
  return __builtin_amdgcn_mfma_f32_16x16x32_bf16(a, b, c, 0, 0, 0);
}

static __device__ __forceinline__ void gload_lds16(const void* g, void* l) {
  __builtin_amdgcn_global_load_lds(
      (const __attribute__((address_space(1))) void*)g,
      (__attribute__((address_space(3))) void*)l, 16, 0, 0);
}

// ---------------- fp32 -> bf16 convert (vectorized) ----------------
struct alignas(8) bh4 { __hip_bfloat16 x, y, z, w; };

__global__ void cvt_bf16(const float* __restrict__ in,
                         __hip_bfloat16* __restrict__ out, int n4) {
  int i = blockIdx.x * blockDim.x + threadIdx.x;
  int stride = gridDim.x * blockDim.x;
  for (; i < n4; i += stride) {
    float4 v = reinterpret_cast<const float4*>(in)[i];
    bh4 o;
    o.x = __float2bfloat16(v.x);
    o.y = __float2bfloat16(v.y);
    o.z = __float2bfloat16(v.z);
    o.w = __float2bfloat16(v.w);
    reinterpret_cast<bh4*>(out)[i] = o;
  }
}

// ---------------- projection GEMM, C[m,o] = sum_d A[m,d]*W[o,d] ------------
// MODE 0: Q + RoPE -> [B,H,S,HD] bf16
// MODE 1: K + RoPE -> [B,H,S,HD] bf16
// MODE 2: V        -> [B,H,HD,S] bf16 (transposed for PV B-fragments)
// MODE 3: out-proj -> [M,N] fp32 (d_out)
template <int MODE>
__global__ __launch_bounds__(256) void gemm_proj(
    const __hip_bfloat16* __restrict__ A,   // [4096][1024]
    const __hip_bfloat16* __restrict__ W,   // [1024][1024] (o,d)
    const float* __restrict__ fcos,         // [2048][32]
    const float* __restrict__ fsin,
    void* __restrict__ outp) {
  __shared__ __hip_bfloat16 sA[128 * 32];
  __shared__ __hip_bfloat16 sB[128 * 32];

  const int tid = threadIdx.x;
  const int wid = tid >> 6;
  const int lane = tid & 63;
  const int l4 = lane >> 4, l16 = lane & 15;
  const int brow = blockIdx.x * 128;   // m
  const int bcol = blockIdx.y * 128;   // o
  const int wr = (wid >> 1) * 64;      // wave row offset in tile
  const int wc = (wid & 1) * 64;       // wave col offset in tile

  f32x4 acc[4][4] = {};

  // staging: chunk c = call*256 + tid ; row = c>>2, col = (c&3)*8 (LDS row-major [128][32])
  const int arow = tid >> 2;           // 0..63 (+64 for call 1)
  const int acol = (tid & 3) * 8;
  const __hip_bfloat16* Ap = A + (size_t)(brow + arow) * 1024 + acol;
  const __hip_bfloat16* Wp = W + (size_t)(bcol + arow) * 1024 + acol;
  __hip_bfloat16* sA0 = sA + wid * 512;   // wave-uniform LDS base (elements)
  __hip_bfloat16* sB0 = sB + wid * 512;

  for (int kt = 0; kt < 32; ++kt) {
    const int k0 = kt * 32;
    __syncthreads();
    gload_lds16(Ap + k0,             sA0);
    gload_lds16(Ap + 64 * 1024 + k0, sA0 + 2048);
    gload_lds16(Wp + k0,             sB0);
    gload_lds16(Wp + 64 * 1024 + k0, sB0 + 2048);
    __syncthreads();

    bf16x8 af[4], bfr[4];
#pragma unroll
    for (int i = 0; i < 4; ++i)
      af[i] = *(const bf16x8*)&sA[(wr + i * 16 + l16) * 32 + l4 * 8];
#pragma unroll
    for (int i = 0; i < 4; ++i)
      bfr[i] = *(const bf16x8*)&sB[(wc + i * 16 + l16) * 32 + l4 * 8];
#pragma unroll
    for (int mi = 0; mi < 4; ++mi)
#pragma unroll
      for (int ni = 0; ni < 4; ++ni)
        acc[mi][ni] = mfma16(af[mi], bfr[ni], acc[mi][ni]);
  }

  // epilogue: C layout col = lane&15, row = (lane>>4)*4 + j
#pragma unroll
  for (int mi = 0; mi < 4; ++mi)
#pragma unroll
    for (int ni = 0; ni < 4; ++ni)
#pragma unroll
      for (int j = 0; j < 4; ++j) {
        float v = acc[mi][ni][j];
        const int row = brow + wr + mi * 16 + l4 * 4 + j;  // m = b*2048 + s
        const int col = bcol + wc + ni * 16 + l16;         // o = h*64 + hd
        if (MODE == 3) {
          ((float*)outp)[(size_t)row * 1024 + col] = v;
        } else if (MODE == 2) {
          const int bb = row >> 11, ss = row & 2047;
          const int hh = col >> 6, hd = col & 63;
          ((__hip_bfloat16*)outp)[((size_t)(bb * 16 + hh) * 64 + hd) * 2048 + ss] =
              __float2bfloat16(v);
        } else {
          // RoPE: pair partner (col^1) sits in lane^1 with same (mi,ni,j)
          float other = __shfl_xor(v, 1);
          const int ss = row & 2047;
          const int p = (col & 63) >> 1;
          const float c = fcos[ss * 32 + p];
          const float sn = fsin[ss * 32 + p];
          const float r = (col & 1) ? (other * sn + v * c) : (v * c - other * sn);
          const int bb = row >> 11;
          const int hh = col >> 6, hd = col & 63;
          ((__hip_bfloat16*)outp)[((size_t)(bb * 16 + hh) * 2048 + ss) * 64 + hd] =
              __float2bfloat16(r);
        }
      }
}

// ---------------- flash attention ----------------
// grid = (S/128, B*H), 256 threads (4 waves), wave w owns q rows [qt*128+w*32, +32)
__global__ __launch_bounds__(256) void attn_fwd(
    const __hip_bfloat16* __restrict__ Q,   // [B,H,S,64]
    const __hip_bfloat16* __restrict__ K,   // [B,H,S,64]
    const __hip_bfloat16* __restrict__ VT,  // [B,H,64,S]
    __hip_bfloat16* __restrict__ AO) {      // [B,S,1024] (col = h*64+hd)
  const int qt = blockIdx.x;
  const int bh = blockIdx.y;
  const int bb = bh >> 4;
  const int hh = bh & 15;
  const int tid = threadIdx.x;
  const int wid = tid >> 6;
  const int lane = tid & 63;
  const int l4 = lane >> 4, l16 = lane & 15;
  const int wq0 = qt * 128 + wid * 32;

  const __hip_bfloat16* Qg = Q + (size_t)bh * 2048 * 64;
  const __hip_bfloat16* Kg = K + (size_t)bh * 2048 * 64;
  const __hip_bfloat16* Vg = VT + (size_t)bh * 64 * 2048;

  __shared__ __hip_bfloat16 sK[64][72];      // K tile, padded (2-way bank alias = free)
  __shared__ __hip_bfloat16 sV[64][72];      // V^T tile [d][k]
  __shared__ __hip_bfloat16 sP[4][32][72];   // per-wave P

  // Q fragments straight from global (contiguous 16B per lane)
  bf16x8 qf[2][2];
#pragma unroll
  for (int mf = 0; mf < 2; ++mf)
#pragma unroll
    for (int dk = 0; dk < 2; ++dk)
      qf[mf][dk] = *(const bf16x8*)&Qg[(size_t)(wq0 + mf * 16 + l16) * 64 + dk * 32 + l4 * 8];

  float mrun[2][4], lrun[2][4];
  f32x4 oacc[2][4];
#pragma unroll
  for (int mf = 0; mf < 2; ++mf)
#pragma unroll
    for (int j = 0; j < 4; ++j) { mrun[mf][j] = -1e30f; lrun[mf][j] = 0.f; }
#pragma unroll
  for (int mf = 0; mf < 2; ++mf)
#pragma unroll
    for (int df = 0; df < 4; ++df) oacc[mf][df] = (f32x4){0.f, 0.f, 0.f, 0.f};

  const int nkv = 2 * qt + 2;
  for (int kv = 0; kv < nkv; ++kv) {
    const int kb = kv * 64;
    __syncthreads();
    // stage K [64 rows][64] and V^T [64 rows][64] (128B/row = 8 x 16B chunks)
#pragma unroll
    for (int i = 0; i < 2; ++i) {
      const int c = i * 256 + tid;
      const int r = c >> 3, o8 = (c & 7) * 8;
      *(uint4*)&sK[r][o8] = *(const uint4*)&Kg[(size_t)(kb + r) * 64 + o8];
      *(uint4*)&sV[r][o8] = *(const uint4*)&Vg[(size_t)r * 2048 + kb + o8];
    }
    __syncthreads();

    // scores S = Q K^T : C rows = q, cols = k
    f32x4 sacc[2][4];
#pragma unroll
    for (int mf = 0; mf < 2; ++mf)
#pragma unroll
      for (int nf = 0; nf < 4; ++nf) sacc[mf][nf] = (f32x4){0.f, 0.f, 0.f, 0.f};
#pragma unroll
    for (int dk = 0; dk < 2; ++dk) {
      bf16x8 kfr[4];
#pragma unroll
      for (int nf = 0; nf < 4; ++nf)
        kfr[nf] = *(const bf16x8*)&sK[nf * 16 + l16][dk * 32 + l4 * 8];
#pragma unroll
      for (int mf = 0; mf < 2; ++mf)
#pragma unroll
        for (int nf = 0; nf < 4; ++nf)
          sacc[mf][nf] = mfma16(qf[mf][dk], kfr[nf], sacc[mf][nf]);
    }

    // online softmax (row reduction across the 16-lane col group)
#pragma unroll
    for (int mf = 0; mf < 2; ++mf)
#pragma unroll
      for (int j = 0; j < 4; ++j) {
        const int qrow = wq0 + mf * 16 + l4 * 4 + j;
        float vals[4];
#pragma unroll
        for (int nf = 0; nf < 4; ++nf) {
          const int kcol = kb + nf * 16 + l16;
          float sv = sacc[mf][nf][j] * 0.125f;
          if (kcol > qrow) sv = -1e9f;
          vals[nf] = sv;
        }
        float mx = fmaxf(fmaxf(vals[0], vals[1]), fmaxf(vals[2], vals[3]));
#pragma unroll
        for (int d = 1; d < 16; d <<= 1) mx = fmaxf(mx, __shfl_xor(mx, d));
        const float mold = mrun[mf][j];
        const float mnew = fmaxf(mold, mx);
        const float fac = __expf(mold - mnew);
        float ts = 0.f;
#pragma unroll
        for (int nf = 0; nf < 4; ++nf) {
          const float p = __expf(vals[nf] - mnew);
          ts += p;
          sP[wid][mf * 16 + l4 * 4 + j][nf * 16 + l16] = __float2bfloat16(p);
        }
#pragma unroll
        for (int d = 1; d < 16; d <<= 1) ts += __shfl_xor(ts, d);
        mrun[mf][j] = mnew;
        lrun[mf][j] = lrun[mf][j] * fac + ts;
#pragma unroll
        for (int df = 0; df < 4; ++df) oacc[mf][df][j] *= fac;
      }
    __syncthreads();

    // O += P V  (A = P rows q, B = V^T cols d)
#pragma unroll
    for (int ks = 0; ks < 2; ++ks) {
      bf16x8 pfr[2], vfr[4];
#pragma unroll
      for (int mf = 0; mf < 2; ++mf)
        pfr[mf] = *(const bf16x8*)&sP[wid][mf * 16 + l16][ks * 32 + l4 * 8];
#pragma unroll
      for (int df = 0; df < 4; ++df)
        vfr[df] = *(const bf16x8*)&sV[df * 16 + l16][ks * 32 + l4 * 8];
#pragma unroll
      for (int mf = 0; mf < 2; ++mf)
#pragma unroll
        for (int df = 0; df < 4; ++df)
          oacc[mf][df] = mfma16(pfr[mf], vfr[df], oacc[mf][df]);
    }
  }

  // normalize and store [B,S,H*64+hd] bf16
#pragma unroll
  for (int mf = 0; mf < 2; ++mf)
#pragma unroll
    for (int df = 0; df < 4; ++df)
#pragma unroll
      for (int j = 0; j < 4; ++j) {
        const int ss = wq0 + mf * 16 + l4 * 4 + j;
        const int dd = hh * 64 + df * 16 + l16;
        const float o = oacc[mf][df][j] / lrun[mf][j];
        AO[((size_t)bb * 2048 + ss) * 1024 + dd] = __float2bfloat16(o);
      }
}

// ---------------- launch ----------------
extern "C" void kernel_launch(void* const* d_in, const int* in_sizes, int n_in,
                              void* d_out, int out_size, void* d_ws, size_t ws_size,
                              hipStream_t stream) {
  const float* x  = (const float*)d_in[0];
  const float* wq = (const float*)d_in[1];
  const float* wk = (const float*)d_in[2];
  const float* wv = (const float*)d_in[3];
  const float* wo = (const float*)d_in[4];
  const float* fc = (const float*)d_in[5];
  const float* fs = (const float*)d_in[6];
  // d_in[7] = mask: causal tril(-1e9) — implemented directly in attn_fwd

  char* ws = (char*)d_ws;
  const size_t MB = 1024 * 1024;
  __hip_bfloat16* xb  = (__hip_bfloat16*)(ws);              // 8 MB
  __hip_bfloat16* wqb = (__hip_bfloat16*)(ws + 8 * MB);     // 2 MB
  __hip_bfloat16* wkb = (__hip_bfloat16*)(ws + 10 * MB);
  __hip_bfloat16* wvb = (__hip_bfloat16*)(ws + 12 * MB);
  __hip_bfloat16* wob = (__hip_bfloat16*)(ws + 14 * MB);
  __hip_bfloat16* qws = (__hip_bfloat16*)(ws + 16 * MB);    // 8 MB [B,H,S,64]
  __hip_bfloat16* kws = (__hip_bfloat16*)(ws + 24 * MB);    // 8 MB
  __hip_bfloat16* vws = (__hip_bfloat16*)(ws + 32 * MB);    // 8 MB [B,H,64,S]
  __hip_bfloat16* ao  = (__hip_bfloat16*)(ws + 40 * MB);    // 8 MB [B,S,1024]

  cvt_bf16<<<2048, 256, 0, stream>>>(x,  xb,  NM * ND / 4);
  cvt_bf16<<<1024, 256, 0, stream>>>(wq, wqb, ND * ND / 4);
  cvt_bf16<<<1024, 256, 0, stream>>>(wk, wkb, ND * ND / 4);
  cvt_bf16<<<1024, 256, 0, stream>>>(wv, wvb, ND * ND / 4);
  cvt_bf16<<<1024, 256, 0, stream>>>(wo, wob, ND * ND / 4);

  dim3 g(NM / 128, ND / 128);  // 32 x 8
  gemm_proj<0><<<g, 256, 0, stream>>>(xb, wqb, fc, fs, (void*)qws);
  gemm_proj<1><<<g, 256, 0, stream>>>(xb, wkb, fc, fs, (void*)kws);
  gemm_proj<2><<<g, 256, 0, stream>>>(xb, wvb, fc, fs, (void*)vws);

  attn_fwd<<<dim3(NS / 128, NB * NH), 256, 0, stream>>>(qws, kws, vws, ao);

  gemm_proj<3><<<g, 256, 0, stream>>>(ao, wob, fc, fs, d_out);
}

// Round 2
// 268.667 us; speedup vs baseline: 1.3000x; 1.3000x over previous
//
#include <hip/hip_runtime.h>
#include <hip/hip_bf16.h>
#include <stdint.h>

// Problem constants: B=2, S=2048, D=1024, H=16, HD=64
#define NB 2
#define NS 2048
#define ND 1024
#define NH 16
#define NM (NB*NS)   // 4096 rows in the projection GEMMs

typedef __attribute__((ext_vector_type(8))) short bf16x8;
typedef __attribute__((ext_vector_type(4))) float f32x4;

static __device__ __forceinline__ f32x4 mfma16(bf16x8 a, bf16x8 b, f32x4 c) {
  return __builtin_amdgcn_mfma_f32_16x16x32_bf16(a, b, c, 0, 0, 0);
}

static __device__ __forceinline__ void gload_lds16(const void* g, void* l) {
  __builtin_amdgcn_global_load_lds(
      (const __attribute__((address_space(1))) void*)g,
      (__attribute__((address_space(3))) void*)l, 16, 0, 0);
}

static __device__ __forceinline__ uint32_t pkbf2(float a, float b) {
  return (uint32_t)__bfloat16_as_ushort(__float2bfloat16(a)) |
         ((uint32_t)__bfloat16_as_ushort(__float2bfloat16(b)) << 16);
}

// ---------------- fp32 -> bf16 converts ----------------
struct alignas(8) bh4 { __hip_bfloat16 x, y, z, w; };

__global__ void cvt_bf16(const float* __restrict__ in,
                         __hip_bfloat16* __restrict__ out, int n4) {
  int i = blockIdx.x * blockDim.x + threadIdx.x;
  int stride = gridDim.x * blockDim.x;
  for (; i < n4; i += stride) {
    float4 v = reinterpret_cast<const float4*>(in)[i];
    bh4 o;
    o.x = __float2bfloat16(v.x);
    o.y = __float2bfloat16(v.y);
    o.z = __float2bfloat16(v.z);
    o.w = __float2bfloat16(v.w);
    reinterpret_cast<bh4*>(out)[i] = o;
  }
}

// 4 weight matrices (1M elems each), 1024 blocks per tensor, 1 float4/thread
__global__ void cvt_w4(const float* __restrict__ w0, const float* __restrict__ w1,
                       const float* __restrict__ w2, const float* __restrict__ w3,
                       __hip_bfloat16* o0, __hip_bfloat16* o1,
                       __hip_bfloat16* o2, __hip_bfloat16* o3) {
  const int t = blockIdx.x >> 10;
  const float* in = (t == 0) ? w0 : (t == 1) ? w1 : (t == 2) ? w2 : w3;
  __hip_bfloat16* out = (t == 0) ? o0 : (t == 1) ? o1 : (t == 2) ? o2 : o3;
  const int i = (blockIdx.x & 1023) * 256 + threadIdx.x;
  float4 v = reinterpret_cast<const float4*>(in)[i];
  bh4 o;
  o.x = __float2bfloat16(v.x);
  o.y = __float2bfloat16(v.y);
  o.z = __float2bfloat16(v.z);
  o.w = __float2bfloat16(v.w);
  reinterpret_cast<bh4*>(out)[i] = o;
}

// ---------------- projection GEMM, C[m,o] = sum_d A[m,d]*W[o,d] ------------
// BM=128, BN=64, BK=32 -> grid (32,16) = 512 blocks (2/CU)
// MODE 0: Q + RoPE, scaled by 1/8 -> [B,H,S,HD] bf16
// MODE 1: K + RoPE -> [B,H,S,HD] bf16
// MODE 2: V        -> [B,H,HD,S] bf16 (transposed)
// MODE 3: out-proj -> [M,N] fp32 (d_out)
template <int MODE>
__global__ __launch_bounds__(256) void gemm_proj(
    const __hip_bfloat16* __restrict__ A,   // [4096][1024]
    const __hip_bfloat16* __restrict__ W,   // [1024][1024] (o,d)
    const float* __restrict__ fcos,         // [2048][32]
    const float* __restrict__ fsin,
    void* __restrict__ outp) {
  __shared__ __hip_bfloat16 sA[128 * 32];
  __shared__ __hip_bfloat16 sB[64 * 32];

  const int tid = threadIdx.x;
  const int wid = tid >> 6;
  const int lane = tid & 63;
  const int l4 = lane >> 4, l16 = lane & 15;
  const int brow = blockIdx.x * 128;   // m
  const int bcol = blockIdx.y * 64;    // o
  const int wr = (wid >> 1) * 64;      // wave row offset
  const int wc = (wid & 1) * 32;       // wave col offset

  f32x4 acc[4][2] = {};

  const __hip_bfloat16* Ap = A + (size_t)(brow + (tid >> 2)) * 1024 + (tid & 3) * 8;
  const __hip_bfloat16* Wp = W + (size_t)(bcol + (tid >> 2)) * 1024 + (tid & 3) * 8;
  char* sAc = (char*)sA + wid * 1024;
  char* sBc = (char*)sB + wid * 1024;

  for (int kt = 0; kt < 32; ++kt) {
    const int k0 = kt * 32;
    __syncthreads();
    gload_lds16(Ap + k0,             sAc);
    gload_lds16(Ap + 64 * 1024 + k0, sAc + 4096);
    gload_lds16(Wp + k0,             sBc);
    __syncthreads();

    bf16x8 af[4], bfr[2];
#pragma unroll
    for (int i = 0; i < 4; ++i)
      af[i] = *(const bf16x8*)&sA[(wr + i * 16 + l16) * 32 + l4 * 8];
#pragma unroll
    for (int i = 0; i < 2; ++i)
      bfr[i] = *(const bf16x8*)&sB[(wc + i * 16 + l16) * 32 + l4 * 8];
#pragma unroll
    for (int mi = 0; mi < 4; ++mi)
#pragma unroll
      for (int ni = 0; ni < 2; ++ni)
        acc[mi][ni] = mfma16(af[mi], bfr[ni], acc[mi][ni]);
  }

  // epilogue: C layout col = lane&15, row = (lane>>4)*4 + j
#pragma unroll
  for (int mi = 0; mi < 4; ++mi)
#pragma unroll
    for (int ni = 0; ni < 2; ++ni)
#pragma unroll
      for (int j = 0; j < 4; ++j) {
        float v = acc[mi][ni][j];
        const int row = brow + wr + mi * 16 + l4 * 4 + j;  // m = b*2048 + s
        const int col = bcol + wc + ni * 16 + l16;         // o = h*64 + hd
        if (MODE == 3) {
          ((float*)outp)[(size_t)row * 1024 + col] = v;
        } else if (MODE == 2) {
          const int bb = row >> 11, ss = row & 2047;
          const int hh = col >> 6, hd = col & 63;
          ((__hip_bfloat16*)outp)[((size_t)(bb * 16 + hh) * 64 + hd) * 2048 + ss] =
              __float2bfloat16(v);
        } else {
          // RoPE: pair partner (col^1) sits in lane^1 with same (mi,ni,j)
          float other = __shfl_xor(v, 1);
          const int ss = row & 2047;
          const int p = (col & 63) >> 1;
          const float c = fcos[ss * 32 + p];
          const float sn = fsin[ss * 32 + p];
          float r = (col & 1) ? (other * sn + v * c) : (v * c - other * sn);
          if (MODE == 0) r *= 0.125f;  // fold 1/sqrt(64) into Q (exact in bf16)
          const int bb = row >> 11;
          const int hh = col >> 6, hd = col & 63;
          ((__hip_bfloat16*)outp)[((size_t)(bb * 16 + hh) * 2048 + ss) * 64 + hd] =
              __float2bfloat16(r);
        }
      }
}

// ---------------- flash attention ----------------
// 512 blocks of 256 threads. Linear block id L remapped for balance:
//   L<256: qt = 15-(L>>5) (heavy, dispatched first), L>=256: qt = (L>>5)-8.
// Co-resident pairs (L, L+256) then sum to constant work (34 KV-tiles).
// Swapped QK^T (mfma(K,Q)) -> lane-local score rows; dbuf K/V LDS; 1 barrier/tile.
__global__ __launch_bounds__(256) void attn_fwd(
    const __hip_bfloat16* __restrict__ Q,   // [B,H,S,64] (pre-scaled by 1/8)
    const __hip_bfloat16* __restrict__ K,   // [B,H,S,64]
    const __hip_bfloat16* __restrict__ VT,  // [B,H,64,S]
    __hip_bfloat16* __restrict__ AO) {      // [B,S,1024]
  const int L = blockIdx.x;
  int qt, bh;
  if (L < 256) { qt = 15 - (L >> 5); bh = L & 31; }
  else         { qt = (L >> 5) - 8;  bh = L & 31; }
  const int bb = bh >> 4;
  const int hh = bh & 15;
  const int tid = threadIdx.x;
  const int wid = tid >> 6;
  const int lane = tid & 63;
  const int l4 = lane >> 4, l16 = lane & 15;
  const int wq0 = qt * 128 + wid * 32;

  const __hip_bfloat16* Qg = Q + (size_t)bh * 2048 * 64;
  const __hip_bfloat16* Kg = K + (size_t)bh * 2048 * 64;
  const __hip_bfloat16* Vg = VT + (size_t)bh * 64 * 2048;

  __shared__ __hip_bfloat16 sK[2][64][72];   // K tile dbuf (pad: even b128 banks)
  __shared__ __hip_bfloat16 sV[2][64][72];   // V^T tile dbuf [d][k]
  __shared__ __hip_bfloat16 sP[4][32][72];   // per-wave P (no barrier needed)

  // Q fragments (used as MFMA B-operand: layout [q=l16][d consecutive])
  bf16x8 qf[2][2];
#pragma unroll
  for (int q2 = 0; q2 < 2; ++q2)
#pragma unroll
    for (int dk = 0; dk < 2; ++dk)
      qf[q2][dk] = *(const bf16x8*)&Qg[(size_t)(wq0 + q2 * 16 + l16) * 64 + dk * 32 + l4 * 8];

  float mrun[2] = {-1e30f, -1e30f};   // per-lane stats for q = wq0 + q2*16 + l16
  float lrun[2] = {0.f, 0.f};
  f32x4 oacc[2][4] = {};              // O rows q=(l4,j), cols d=l16

  const int sr = tid >> 3;            // staging: row within 32-row half
  const int so = (tid & 7) * 8;       // col (elements)
  const int nkv = 2 * qt + 2;

  // prologue: stage tile 0 into buffer 0
  uint4 kreg[2], vreg[2];
#pragma unroll
  for (int i = 0; i < 2; ++i) {
    kreg[i] = *(const uint4*)&Kg[(size_t)(i * 32 + sr) * 64 + so];
    vreg[i] = *(const uint4*)&Vg[(size_t)(i * 32 + sr) * 2048 + so];
  }
#pragma unroll
  for (int i = 0; i < 2; ++i) {
    *(uint4*)&sK[0][i * 32 + sr][so] = kreg[i];
    *(uint4*)&sV[0][i * 32 + sr][so] = vreg[i];
  }
  __syncthreads();

  for (int kv = 0; kv < nkv; ++kv) {
    const int cur = kv & 1, nxt = cur ^ 1;
    const int kb = kv * 64;

    // issue next tile's loads early (latency hides under compute)
    if (kv + 1 < nkv) {
      const int kb2 = kb + 64;
#pragma unroll
      for (int i = 0; i < 2; ++i) {
        kreg[i] = *(const uint4*)&Kg[(size_t)(kb2 + i * 32 + sr) * 64 + so];
        vreg[i] = *(const uint4*)&Vg[(size_t)(i * 32 + sr) * 2048 + kb2 + so];
      }
    }

    if (kb <= wq0 + 31) {   // this wave has live rows in this tile
      // swapped QK^T: C[k=(l4,j)][q=l16]
      f32x4 sacc[4][2] = {};
#pragma unroll
      for (int dk = 0; dk < 2; ++dk) {
        bf16x8 kfr[4];
#pragma unroll
        for (int kf = 0; kf < 4; ++kf)
          kfr[kf] = *(const bf16x8*)&sK[cur][kf * 16 + l16][dk * 32 + l4 * 8];
#pragma unroll
        for (int kf = 0; kf < 4; ++kf)
#pragma unroll
          for (int q2 = 0; q2 < 2; ++q2)
            sacc[kf][q2] = mfma16(kfr[kf], qf[q2][dk], sacc[kf][q2]);
      }

      const bool need_mask = (kb + 63 > wq0);  // only the diagonal tile
      float fac[2];
#pragma unroll
      for (int q2 = 0; q2 < 2; ++q2) {
        const int qi = wq0 + q2 * 16 + l16;
        float pv[16];
#pragma unroll
        for (int kf = 0; kf < 4; ++kf)
#pragma unroll
          for (int j = 0; j < 4; ++j) {
            float s = sacc[kf][q2][j];
            if (need_mask && (kb + kf * 16 + l4 * 4 + j > qi)) s = -1e30f;
            pv[kf * 4 + j] = s;
          }
        float m0 = fmaxf(fmaxf(pv[0], pv[1]), fmaxf(pv[2], pv[3]));
        float m1 = fmaxf(fmaxf(pv[4], pv[5]), fmaxf(pv[6], pv[7]));
        float m2 = fmaxf(fmaxf(pv[8], pv[9]), fmaxf(pv[10], pv[11]));
        float m3 = fmaxf(fmaxf(pv[12], pv[13]), fmaxf(pv[14], pv[15]));
        float mloc = fmaxf(fmaxf(m0, m1), fmaxf(m2, m3));
        mloc = fmaxf(mloc, __shfl_xor(mloc, 16));
        mloc = fmaxf(mloc, __shfl_xor(mloc, 32));
        const float mold = mrun[q2];
        const float mnew = fmaxf(mold, mloc);
        const float f = __expf(mold - mnew);
        fac[q2] = f;
        mrun[q2] = mnew;
        float ts = 0.f;
        float pe[16];
#pragma unroll
        for (int t = 0; t < 16; ++t) { pe[t] = __expf(pv[t] - mnew); ts += pe[t]; }
#pragma unroll
        for (int kf = 0; kf < 4; ++kf) {
          uint2 w;
          w.x = pkbf2(pe[kf * 4 + 0], pe[kf * 4 + 1]);
          w.y = pkbf2(pe[kf * 4 + 2], pe[kf * 4 + 3]);
          *(uint2*)&sP[wid][q2 * 16 + l16][kf * 16 + l4 * 4] = w;
        }
        ts += __shfl_xor(ts, 16);
        ts += __shfl_xor(ts, 32);
        lrun[q2] = lrun[q2] * f + ts;
      }

      // rescale O: row q=(l4,j) needs fac from lane l16 = l4*4+j
#pragma unroll
      for (int mf = 0; mf < 2; ++mf)
#pragma unroll
        for (int j = 0; j < 4; ++j) {
          const float fr = __shfl(fac[mf], l4 * 4 + j);
#pragma unroll
          for (int df = 0; df < 4; ++df) oacc[mf][df][j] *= fr;
        }

      // O += P V (A-operand P rows q, B-operand V^T rows d)
#pragma unroll
      for (int ks = 0; ks < 2; ++ks) {
        bf16x8 pfr[2], vfr[4];
#pragma unroll
        for (int mf = 0; mf < 2; ++mf)
          pfr[mf] = *(const bf16x8*)&sP[wid][mf * 16 + l16][ks * 32 + l4 * 8];
#pragma unroll
        for (int df = 0; df < 4; ++df)
          vfr[df] = *(const bf16x8*)&sV[cur][df * 16 + l16][ks * 32 + l4 * 8];
#pragma unroll
        for (int mf = 0; mf < 2; ++mf)
#pragma unroll
          for (int df = 0; df < 4; ++df)
            oacc[mf][df] = mfma16(pfr[mf], vfr[df], oacc[mf][df]);
      }
    }

    // write next tile into the other buffer, then single barrier
    if (kv + 1 < nkv) {
#pragma unroll
      for (int i = 0; i < 2; ++i) {
        *(uint4*)&sK[nxt][i * 32 + sr][so] = kreg[i];
        *(uint4*)&sV[nxt][i * 32 + sr][so] = vreg[i];
      }
    }
    __syncthreads();
  }

  // normalize and store [B,S,H*64+hd] bf16
  float inv[2];
#pragma unroll
  for (int q2 = 0; q2 < 2; ++q2) inv[q2] = 1.f / lrun[q2];
#pragma unroll
  for (int mf = 0; mf < 2; ++mf)
#pragma unroll
    for (int j = 0; j < 4; ++j) {
      const float ir = __shfl(inv[mf], l4 * 4 + j);
      const int ss = wq0 + mf * 16 + l4 * 4 + j;
#pragma unroll
      for (int df = 0; df < 4; ++df) {
        const int dd = hh * 64 + df * 16 + l16;
        AO[((size_t)bb * 2048 + ss) * 1024 + dd] =
            __float2bfloat16(oacc[mf][df][j] * ir);
      }
    }
}

// ---------------- launch ----------------
extern "C" void kernel_launch(void* const* d_in, const int* in_sizes, int n_in,
                              void* d_out, int out_size, void* d_ws, size_t ws_size,
                              hipStream_t stream) {
  const float* x  = (const float*)d_in[0];
  const float* wq = (const float*)d_in[1];
  const float* wk = (const float*)d_in[2];
  const float* wv = (const float*)d_in[3];
  const float* wo = (const float*)d_in[4];
  const float* fc = (const float*)d_in[5];
  const float* fs = (const float*)d_in[6];

  char* ws = (char*)d_ws;
  const size_t MB = 1024 * 1024;
  __hip_bfloat16* xb  = (__hip_bfloat16*)(ws);              // 8 MB
  __hip_bfloat16* wqb = (__hip_bfloat16*)(ws + 8 * MB);     // 2 MB each
  __hip_bfloat16* wkb = (__hip_bfloat16*)(ws + 10 * MB);
  __hip_bfloat16* wvb = (__hip_bfloat16*)(ws + 12 * MB);
  __hip_bfloat16* wob = (__hip_bfloat16*)(ws + 14 * MB);
  __hip_bfloat16* qws = (__hip_bfloat16*)(ws + 16 * MB);    // [B,H,S,64]
  __hip_bfloat16* kws = (__hip_bfloat16*)(ws + 24 * MB);
  __hip_bfloat16* vws = (__hip_bfloat16*)(ws + 32 * MB);    // [B,H,64,S]
  __hip_bfloat16* ao  = (__hip_bfloat16*)(ws + 40 * MB);    // [B,S,1024]

  cvt_bf16<<<2048, 256, 0, stream>>>(x, xb, NM * ND / 4);
  cvt_w4<<<4096, 256, 0, stream>>>(wq, wk, wv, wo, wqb, wkb, wvb, wob);

  dim3 g(NM / 128, ND / 64);  // 32 x 16 = 512 blocks
  gemm_proj<0><<<g, 256, 0, stream>>>(xb, wqb, fc, fs, (void*)qws);
  gemm_proj<1><<<g, 256, 0, stream>>>(xb, wkb, fc, fs, (void*)kws);
  gemm_proj<2><<<g, 256, 0, stream>>>(xb, wvb, fc, fs, (void*)vws);

  attn_fwd<<<dim3(512), 256, 0, stream>>>(qws, kws, vws, ao);

  gemm_proj<3><<<g, 256, 0, stream>>>(ao, wob, fc, fs, d_out);
}

// Round 4
// 246.456 us; speedup vs baseline: 1.4172x; 1.0901x over previous
//
#include <hip/hip_runtime.h>
#include <hip/hip_bf16.h>
#include <stdint.h>

// Problem constants: B=2, S=2048, D=1024, H=16, HD=64
#define NB 2
#define NS 2048
#define ND 1024
#define NH 16
#define NM (NB*NS)   // 4096 rows in the projection GEMMs

typedef __attribute__((ext_vector_type(8))) short bf16x8;
typedef __attribute__((ext_vector_type(4))) float f32x4;

static __device__ __forceinline__ f32x4 mfma16(bf16x8 a, bf16x8 b, f32x4 c) {
  return __builtin_amdgcn_mfma_f32_16x16x32_bf16(a, b, c, 0, 0, 0);
}

static __device__ __forceinline__ void gload_lds16(const void* g, void* l) {
  __builtin_amdgcn_global_load_lds(
      (const __attribute__((address_space(1))) void*)g,
      (__attribute__((address_space(3))) void*)l, 16, 0, 0);
}

static __device__ __forceinline__ uint32_t pkbf2(float a, float b) {
  return (uint32_t)__bfloat16_as_ushort(__float2bfloat16(a)) |
         ((uint32_t)__bfloat16_as_ushort(__float2bfloat16(b)) << 16);
}

// scale folded into Q projection: 1/sqrt(64) * log2(e)
#define QSCALE 0.18033688011112042f

// ---------------- fp32 -> bf16 converts ----------------
struct alignas(8) bh4 { __hip_bfloat16 x, y, z, w; };

__global__ void cvt_bf16(const float* __restrict__ in,
                         __hip_bfloat16* __restrict__ out, int n4) {
  int i = blockIdx.x * blockDim.x + threadIdx.x;
  int stride = gridDim.x * blockDim.x;
  for (; i < n4; i += stride) {
    float4 v = reinterpret_cast<const float4*>(in)[i];
    bh4 o;
    o.x = __float2bfloat16(v.x);
    o.y = __float2bfloat16(v.y);
    o.z = __float2bfloat16(v.z);
    o.w = __float2bfloat16(v.w);
    reinterpret_cast<bh4*>(out)[i] = o;
  }
}

__global__ void cvt_w4(const float* __restrict__ w0, const float* __restrict__ w1,
                       const float* __restrict__ w2, const float* __restrict__ w3,
                       __hip_bfloat16* o0, __hip_bfloat16* o1,
                       __hip_bfloat16* o2, __hip_bfloat16* o3) {
  const int t = blockIdx.x >> 10;
  const float* in = (t == 0) ? w0 : (t == 1) ? w1 : (t == 2) ? w2 : w3;
  __hip_bfloat16* out = (t == 0) ? o0 : (t == 1) ? o1 : (t == 2) ? o2 : o3;
  const int i = (blockIdx.x & 1023) * 256 + threadIdx.x;
  float4 v = reinterpret_cast<const float4*>(in)[i];
  bh4 o;
  o.x = __float2bfloat16(v.x);
  o.y = __float2bfloat16(v.y);
  o.z = __float2bfloat16(v.z);
  o.w = __float2bfloat16(v.w);
  reinterpret_cast<bh4*>(out)[i] = o;
}

// ---------------- fused QKV GEMM ------------------------------------------
// C[m,o] = sum_d A[m,d]*W[o,d];  BM=128, BN=64, BK=32
// grid (32, 48): y>>4 selects {Wq, Wk, Wv}; 1536 blocks = 6/CU.
__global__ __launch_bounds__(256) void gemm_qkv(
    const __hip_bfloat16* __restrict__ A,    // [4096][1024]
    const __hip_bfloat16* __restrict__ Wq,
    const __hip_bfloat16* __restrict__ Wk,
    const __hip_bfloat16* __restrict__ Wv,
    const float* __restrict__ fcos,          // [2048][32]
    const float* __restrict__ fsin,
    __hip_bfloat16* __restrict__ Qo,         // [B,H,S,64] (pre-scaled)
    __hip_bfloat16* __restrict__ Ko,         // [B,H,S,64]
    __hip_bfloat16* __restrict__ Vo) {       // [B,H,64,S]
  __shared__ __hip_bfloat16 sA[128 * 32];
  __shared__ __hip_bfloat16 sB[64 * 32];

  const int wsel = blockIdx.y >> 4;
  const __hip_bfloat16* W = (wsel == 0) ? Wq : (wsel == 1) ? Wk : Wv;

  const int tid = threadIdx.x;
  const int wid = tid >> 6;
  const int lane = tid & 63;
  const int l4 = lane >> 4, l16 = lane & 15;
  const int brow = blockIdx.x * 128;
  const int bcol = (blockIdx.y & 15) * 64;
  const int wr = (wid >> 1) * 64;
  const int wc = (wid & 1) * 32;

  f32x4 acc[4][2] = {};

  const __hip_bfloat16* Ap = A + (size_t)(brow + (tid >> 2)) * 1024 + (tid & 3) * 8;
  const __hip_bfloat16* Wp = W + (size_t)(bcol + (tid >> 2)) * 1024 + (tid & 3) * 8;
  char* sAc = (char*)sA + wid * 1024;
  char* sBc = (char*)sB + wid * 1024;

  for (int kt = 0; kt < 32; ++kt) {
    const int k0 = kt * 32;
    __syncthreads();
    gload_lds16(Ap + k0,             sAc);
    gload_lds16(Ap + 64 * 1024 + k0, sAc + 4096);
    gload_lds16(Wp + k0,             sBc);
    __syncthreads();

    bf16x8 af[4], bfr[2];
#pragma unroll
    for (int i = 0; i < 4; ++i)
      af[i] = *(const bf16x8*)&sA[(wr + i * 16 + l16) * 32 + l4 * 8];
#pragma unroll
    for (int i = 0; i < 2; ++i)
      bfr[i] = *(const bf16x8*)&sB[(wc + i * 16 + l16) * 32 + l4 * 8];
#pragma unroll
    for (int mi = 0; mi < 4; ++mi)
#pragma unroll
      for (int ni = 0; ni < 2; ++ni)
        acc[mi][ni] = mfma16(af[mi], bfr[ni], acc[mi][ni]);
  }

#pragma unroll
  for (int mi = 0; mi < 4; ++mi)
#pragma unroll
    for (int ni = 0; ni < 2; ++ni)
#pragma unroll
      for (int j = 0; j < 4; ++j) {
        float v = acc[mi][ni][j];
        const int row = brow + wr + mi * 16 + l4 * 4 + j;  // m = b*2048 + s
        const int col = bcol + wc + ni * 16 + l16;         // o = h*64 + hd
        const int bb = row >> 11, ss = row & 2047;
        const int hh = col >> 6, hd = col & 63;
        if (wsel == 2) {
          Vo[((size_t)(bb * 16 + hh) * 64 + hd) * 2048 + ss] = __float2bfloat16(v);
        } else {
          float other = __shfl_xor(v, 1);
          const int p = hd >> 1;
          const float c = fcos[ss * 32 + p];
          const float sn = fsin[ss * 32 + p];
          float r = (col & 1) ? (other * sn + v * c) : (v * c - other * sn);
          __hip_bfloat16* dst = (wsel == 0) ? Qo : Ko;
          if (wsel == 0) r *= QSCALE;
          dst[((size_t)(bb * 16 + hh) * 2048 + ss) * 64 + hd] = __float2bfloat16(r);
        }
      }
}

// ---------------- out-projection GEMM -> fp32 d_out ----------------
__global__ __launch_bounds__(256) void gemm_out(
    const __hip_bfloat16* __restrict__ A,    // [4096][1024]
    const __hip_bfloat16* __restrict__ W,    // [1024][1024]
    float* __restrict__ C) {
  __shared__ __hip_bfloat16 sA[128 * 32];
  __shared__ __hip_bfloat16 sB[64 * 32];

  const int tid = threadIdx.x;
  const int wid = tid >> 6;
  const int lane = tid & 63;
  const int l4 = lane >> 4, l16 = lane & 15;
  const int brow = blockIdx.x * 128;
  const int bcol = blockIdx.y * 64;
  const int wr = (wid >> 1) * 64;
  const int wc = (wid & 1) * 32;

  f32x4 acc[4][2] = {};

  const __hip_bfloat16* Ap = A + (size_t)(brow + (tid >> 2)) * 1024 + (tid & 3) * 8;
  const __hip_bfloat16* Wp = W + (size_t)(bcol + (tid >> 2)) * 1024 + (tid & 3) * 8;
  char* sAc = (char*)sA + wid * 1024;
  char* sBc = (char*)sB + wid * 1024;

  for (int kt = 0; kt < 32; ++kt) {
    const int k0 = kt * 32;
    __syncthreads();
    gload_lds16(Ap + k0,             sAc);
    gload_lds16(Ap + 64 * 1024 + k0, sAc + 4096);
    gload_lds16(Wp + k0,             sBc);
    __syncthreads();

    bf16x8 af[4], bfr[2];
#pragma unroll
    for (int i = 0; i < 4; ++i)
      af[i] = *(const bf16x8*)&sA[(wr + i * 16 + l16) * 32 + l4 * 8];
#pragma unroll
    for (int i = 0; i < 2; ++i)
      bfr[i] = *(const bf16x8*)&sB[(wc + i * 16 + l16) * 32 + l4 * 8];
#pragma unroll
    for (int mi = 0; mi < 4; ++mi)
#pragma unroll
      for (int ni = 0; ni < 2; ++ni)
        acc[mi][ni] = mfma16(af[mi], bfr[ni], acc[mi][ni]);
  }

#pragma unroll
  for (int mi = 0; mi < 4; ++mi)
#pragma unroll
    for (int ni = 0; ni < 2; ++ni)
#pragma unroll
      for (int j = 0; j < 4; ++j) {
        const int row = brow + wr + mi * 16 + l4 * 4 + j;
        const int col = bcol + wc + ni * 16 + l16;
        C[(size_t)row * 1024 + col] = acc[mi][ni][j];
      }
}

// ---------------- flash attention (barrier-free) ----------------
// 512 blocks of 256 threads; block remap balances work and dispatches
// heavy (high-qt) blocks first. K/V fragments are read DIRECTLY from
// global (L1/L2-resident; identical addresses across the 4 waves). No
// __syncthreads anywhere; only per-wave sP lives in LDS.
__global__ __launch_bounds__(256) void attn_fwd(
    const __hip_bfloat16* __restrict__ Q,   // [B,H,S,64] (pre-scaled, log2 dom)
    const __hip_bfloat16* __restrict__ K,   // [B,H,S,64]
    const __hip_bfloat16* __restrict__ VT,  // [B,H,64,S]
    __hip_bfloat16* __restrict__ AO) {      // [B,S,1024]
  const int L = blockIdx.x;
  int qt, bh;
  if (L < 256) { qt = 15 - (L >> 5); bh = L & 31; }
  else         { qt = (L >> 5) - 8;  bh = L & 31; }
  const int bb = bh >> 4;
  const int hh = bh & 15;
  const int tid = threadIdx.x;
  const int wid = tid >> 6;
  const int lane = tid & 63;
  const int l4 = lane >> 4, l16 = lane & 15;
  const int wq0 = qt * 128 + wid * 32;

  const __hip_bfloat16* Qg = Q + (size_t)bh * 2048 * 64;
  const __hip_bfloat16* Kg = K + (size_t)bh * 2048 * 64;
  const __hip_bfloat16* Vg = VT + (size_t)bh * 64 * 2048;

  __shared__ __hip_bfloat16 sP[4][32][72];   // per-wave P; no barriers needed

  // Q fragments (MFMA B-operand: q = l16, d contiguous)
  bf16x8 qf[2][2];
#pragma unroll
  for (int q2 = 0; q2 < 2; ++q2)
#pragma unroll
    for (int dk = 0; dk < 2; ++dk)
      qf[q2][dk] = *(const bf16x8*)&Qg[(size_t)(wq0 + q2 * 16 + l16) * 64 + dk * 32 + l4 * 8];

  float mrun[2] = {-1e30f, -1e30f};   // log2-domain running max for q = wq0+q2*16+l16
  float lrun[2] = {0.f, 0.f};
  f32x4 oacc[2][4] = {};              // O rows q=(l4,j), cols d=l16

  const int lastkv = (wq0 + 31) >> 6;
  for (int kv = 0; kv <= lastkv; ++kv) {
    const int kb = kv * 64;

    // K fragments direct from global (swapped-QK A-operand: k rows, d cols)
    bf16x8 kfr[4][2];
#pragma unroll
    for (int kf = 0; kf < 4; ++kf)
#pragma unroll
      for (int dk = 0; dk < 2; ++dk)
        kfr[kf][dk] = *(const bf16x8*)&Kg[(size_t)(kb + kf * 16 + l16) * 64 + dk * 32 + l4 * 8];

    // swapped QK^T: C[k=(l4,j)][q=l16]
    f32x4 sacc[4][2] = {};
#pragma unroll
    for (int dk = 0; dk < 2; ++dk)
#pragma unroll
      for (int kf = 0; kf < 4; ++kf)
#pragma unroll
        for (int q2 = 0; q2 < 2; ++q2)
          sacc[kf][q2] = mfma16(kfr[kf][dk], qf[q2][dk], sacc[kf][q2]);

    // V fragments issued now; latency hides under softmax VALU work
    bf16x8 vfr[4][2];
#pragma unroll
    for (int df = 0; df < 4; ++df)
#pragma unroll
      for (int ks = 0; ks < 2; ++ks)
        vfr[df][ks] = *(const bf16x8*)&Vg[(size_t)(df * 16 + l16) * 2048 + kb + ks * 32 + l4 * 8];

    const bool need_mask = (kb + 63 > wq0);  // only the diagonal tile
    float fac[2];
#pragma unroll
    for (int q2 = 0; q2 < 2; ++q2) {
      const int qi = wq0 + q2 * 16 + l16;
      float pv[16];
#pragma unroll
      for (int kf = 0; kf < 4; ++kf)
#pragma unroll
        for (int j = 0; j < 4; ++j) {
          float s = sacc[kf][q2][j];
          if (need_mask && (kb + kf * 16 + l4 * 4 + j > qi)) s = -1e30f;
          pv[kf * 4 + j] = s;
        }
      float m0 = fmaxf(fmaxf(pv[0], pv[1]), fmaxf(pv[2], pv[3]));
      float m1 = fmaxf(fmaxf(pv[4], pv[5]), fmaxf(pv[6], pv[7]));
      float m2 = fmaxf(fmaxf(pv[8], pv[9]), fmaxf(pv[10], pv[11]));
      float m3 = fmaxf(fmaxf(pv[12], pv[13]), fmaxf(pv[14], pv[15]));
      float mloc = fmaxf(fmaxf(m0, m1), fmaxf(m2, m3));
      mloc = fmaxf(mloc, __shfl_xor(mloc, 16));
      mloc = fmaxf(mloc, __shfl_xor(mloc, 32));
      const float mold = mrun[q2];
      const float mnew = fmaxf(mold, mloc);
      const float f = exp2f(mold - mnew);
      fac[q2] = f;
      mrun[q2] = mnew;
      float ts = 0.f;
      float pe[16];
#pragma unroll
      for (int t = 0; t < 16; ++t) { pe[t] = exp2f(pv[t] - mnew); ts += pe[t]; }
#pragma unroll
      for (int kf = 0; kf < 4; ++kf) {
        uint2 w;
        w.x = pkbf2(pe[kf * 4 + 0], pe[kf * 4 + 1]);
        w.y = pkbf2(pe[kf * 4 + 2], pe[kf * 4 + 3]);
        *(uint2*)&sP[wid][q2 * 16 + l16][kf * 16 + l4 * 4] = w;
      }
      ts += __shfl_xor(ts, 16);
      ts += __shfl_xor(ts, 32);
      lrun[q2] = lrun[q2] * f + ts;
    }

    // rescale O: row q=(l4,j) needs fac from lane l16 = l4*4+j
#pragma unroll
    for (int mf = 0; mf < 2; ++mf)
#pragma unroll
      for (int j = 0; j < 4; ++j) {
        const float fr = __shfl(fac[mf], l4 * 4 + j);
#pragma unroll
        for (int df = 0; df < 4; ++df) oacc[mf][df][j] *= fr;
      }

    // O += P V  (P from per-wave LDS; V fragments already in flight)
#pragma unroll
    for (int ks = 0; ks < 2; ++ks) {
      bf16x8 pfr[2];
#pragma unroll
      for (int mf = 0; mf < 2; ++mf)
        pfr[mf] = *(const bf16x8*)&sP[wid][mf * 16 + l16][ks * 32 + l4 * 8];
#pragma unroll
      for (int mf = 0; mf < 2; ++mf)
#pragma unroll
        for (int df = 0; df < 4; ++df)
          oacc[mf][df] = mfma16(pfr[mf], vfr[df][ks], oacc[mf][df]);
    }
  }

  // normalize and store [B,S,H*64+hd] bf16
  float inv[2];
#pragma unroll
  for (int q2 = 0; q2 < 2; ++q2) inv[q2] = 1.f / lrun[q2];
#pragma unroll
  for (int mf = 0; mf < 2; ++mf)
#pragma unroll
    for (int j = 0; j < 4; ++j) {
      const float ir = __shfl(inv[mf], l4 * 4 + j);
      const int ss = wq0 + mf * 16 + l4 * 4 + j;
#pragma unroll
      for (int df = 0; df < 4; ++df) {
        const int dd = hh * 64 + df * 16 + l16;
        AO[((size_t)bb * 2048 + ss) * 1024 + dd] =
            __float2bfloat16(oacc[mf][df][j] * ir);
      }
    }
}

// ---------------- launch ----------------
extern "C" void kernel_launch(void* const* d_in, const int* in_sizes, int n_in,
                              void* d_out, int out_size, void* d_ws, size_t ws_size,
                              hipStream_t stream) {
  const float* x  = (const float*)d_in[0];
  const float* wq = (const float*)d_in[1];
  const float* wk = (const float*)d_in[2];
  const float* wv = (const float*)d_in[3];
  const float* wo = (const float*)d_in[4];
  const float* fc = (const float*)d_in[5];
  const float* fs = (const float*)d_in[6];

  char* ws = (char*)d_ws;
  const size_t MB = 1024 * 1024;
  __hip_bfloat16* xb  = (__hip_bfloat16*)(ws);              // 8 MB
  __hip_bfloat16* wqb = (__hip_bfloat16*)(ws + 8 * MB);     // 2 MB each
  __hip_bfloat16* wkb = (__hip_bfloat16*)(ws + 10 * MB);
  __hip_bfloat16* wvb = (__hip_bfloat16*)(ws + 12 * MB);
  __hip_bfloat16* wob = (__hip_bfloat16*)(ws + 14 * MB);
  __hip_bfloat16* qws = (__hip_bfloat16*)(ws + 16 * MB);    // [B,H,S,64]
  __hip_bfloat16* kws = (__hip_bfloat16*)(ws + 24 * MB);
  __hip_bfloat16* vws = (__hip_bfloat16*)(ws + 32 * MB);    // [B,H,64,S]
  __hip_bfloat16* ao  = (__hip_bfloat16*)(ws + 40 * MB);    // [B,S,1024]

  cvt_bf16<<<2048, 256, 0, stream>>>(x, xb, NM * ND / 4);
  cvt_w4<<<4096, 256, 0, stream>>>(wq, wk, wv, wo, wqb, wkb, wvb, wob);

  gemm_qkv<<<dim3(NM / 128, 48), 256, 0, stream>>>(xb, wqb, wkb, wvb, fc, fs,
                                                   qws, kws, vws);

  attn_fwd<<<dim3(512), 256, 0, stream>>>(qws, kws, vws, ao);

  gemm_out<<<dim3(NM / 128, ND / 64), 256, 0, stream>>>(ao, wob, (float*)d_out);
}

// Round 8
// 244.857 us; speedup vs baseline: 1.4264x; 1.0065x over previous
//
#include <hip/hip_runtime.h>
#include <hip/hip_bf16.h>
#include <stdint.h>

// Problem constants: B=2, S=2048, D=1024, H=16, HD=64
#define NB 2
#define NS 2048
#define ND 1024
#define NH 16
#define NM (NB*NS)   // 4096 rows in the projection GEMMs

typedef __attribute__((ext_vector_type(8))) short bf16x8;
typedef __attribute__((ext_vector_type(4))) float f32x4;

static __device__ __forceinline__ f32x4 mfma16(bf16x8 a, bf16x8 b, f32x4 c) {
  return __builtin_amdgcn_mfma_f32_16x16x32_bf16(a, b, c, 0, 0, 0);
}

static __device__ __forceinline__ void gload_lds16(const void* g, void* l) {
  __builtin_amdgcn_global_load_lds(
      (const __attribute__((address_space(1))) void*)g,
      (__attribute__((address_space(3))) void*)l, 16, 0, 0);
}

static __device__ __forceinline__ uint32_t pkbf2(float a, float b) {
  return (uint32_t)__bfloat16_as_ushort(__float2bfloat16(a)) |
         ((uint32_t)__bfloat16_as_ushort(__float2bfloat16(b)) << 16);
}

// scale folded into Q projection: 1/sqrt(64) * log2(e)
#define QSCALE 0.18033688011112042f

// ---------------- fp32 -> bf16 converts ----------------
struct alignas(8) bh4 { __hip_bfloat16 x, y, z, w; };

__global__ void cvt_bf16(const float* __restrict__ in,
                         __hip_bfloat16* __restrict__ out, int n4) {
  int i = blockIdx.x * blockDim.x + threadIdx.x;
  int stride = gridDim.x * blockDim.x;
  for (; i < n4; i += stride) {
    float4 v = reinterpret_cast<const float4*>(in)[i];
    bh4 o;
    o.x = __float2bfloat16(v.x);
    o.y = __float2bfloat16(v.y);
    o.z = __float2bfloat16(v.z);
    o.w = __float2bfloat16(v.w);
    reinterpret_cast<bh4*>(out)[i] = o;
  }
}

__global__ void cvt_w4(const float* __restrict__ w0, const float* __restrict__ w1,
                       const float* __restrict__ w2, const float* __restrict__ w3,
                       __hip_bfloat16* o0, __hip_bfloat16* o1,
                       __hip_bfloat16* o2, __hip_bfloat16* o3) {
  const int t = blockIdx.x >> 10;
  const float* in = (t == 0) ? w0 : (t == 1) ? w1 : (t == 2) ? w2 : w3;
  __hip_bfloat16* out = (t == 0) ? o0 : (t == 1) ? o1 : (t == 2) ? o2 : o3;
  const int i = (blockIdx.x & 1023) * 256 + threadIdx.x;
  float4 v = reinterpret_cast<const float4*>(in)[i];
  bh4 o;
  o.x = __float2bfloat16(v.x);
  o.y = __float2bfloat16(v.y);
  o.z = __float2bfloat16(v.z);
  o.w = __float2bfloat16(v.w);
  reinterpret_cast<bh4*>(out)[i] = o;
}

// ---------------- fused QKV GEMM (m97 structure: 128x128, BK=32) -----------
// C[m,o] = sum_d A[m,d]*W[o,d]; grid (32, 24): y>>3 selects {Wq,Wk,Wv}.
// 4 waves, each owns a 64x64 quadrant (4x4 x 16x16 fragments).
__global__ __launch_bounds__(256) void gemm_qkv(
    const __hip_bfloat16* __restrict__ A,    // [4096][1024]
    const __hip_bfloat16* __restrict__ Wq,
    const __hip_bfloat16* __restrict__ Wk,
    const __hip_bfloat16* __restrict__ Wv,
    const float* __restrict__ fcos,          // [2048][32]
    const float* __restrict__ fsin,
    __hip_bfloat16* __restrict__ Qo,         // [B,H,S,64] (pre-scaled, log2 dom)
    __hip_bfloat16* __restrict__ Ko,         // [B,H,S,64]
    __hip_bfloat16* __restrict__ Vo) {       // [B,H,64,S]
  __shared__ __hip_bfloat16 sA[128 * 32];
  __shared__ __hip_bfloat16 sB[128 * 32];

  const int wsel = blockIdx.y >> 3;
  const __hip_bfloat16* W = (wsel == 0) ? Wq : (wsel == 1) ? Wk : Wv;

  const int tid = threadIdx.x;
  const int wid = tid >> 6;
  const int lane = tid & 63;
  const int l4 = lane >> 4, l16 = lane & 15;
  const int brow = blockIdx.x * 128;
  const int bcol = (blockIdx.y & 7) * 128;
  const int wr = (wid >> 1) * 64;
  const int wc = (wid & 1) * 64;

  f32x4 acc[4][4] = {};

  const __hip_bfloat16* Ap = A + (size_t)(brow + (tid >> 2)) * 1024 + (tid & 3) * 8;
  const __hip_bfloat16* Wp = W + (size_t)(bcol + (tid >> 2)) * 1024 + (tid & 3) * 8;
  char* sAc = (char*)sA + wid * 1024;
  char* sBc = (char*)sB + wid * 1024;

  for (int kt = 0; kt < 32; ++kt) {
    const int k0 = kt * 32;
    __syncthreads();
    gload_lds16(Ap + k0,             sAc);
    gload_lds16(Ap + 64 * 1024 + k0, sAc + 4096);
    gload_lds16(Wp + k0,             sBc);
    gload_lds16(Wp + 64 * 1024 + k0, sBc + 4096);
    __syncthreads();

    bf16x8 af[4], bfr[4];
#pragma unroll
    for (int i = 0; i < 4; ++i)
      af[i] = *(const bf16x8*)&sA[(wr + i * 16 + l16) * 32 + l4 * 8];
#pragma unroll
    for (int i = 0; i < 4; ++i)
      bfr[i] = *(const bf16x8*)&sB[(wc + i * 16 + l16) * 32 + l4 * 8];
#pragma unroll
    for (int mi = 0; mi < 4; ++mi)
#pragma unroll
      for (int ni = 0; ni < 4; ++ni)
        acc[mi][ni] = mfma16(af[mi], bfr[ni], acc[mi][ni]);
  }

#pragma unroll
  for (int mi = 0; mi < 4; ++mi)
#pragma unroll
    for (int ni = 0; ni < 4; ++ni)
#pragma unroll
      for (int j = 0; j < 4; ++j) {
        float v = acc[mi][ni][j];
        const int row = brow + wr + mi * 16 + l4 * 4 + j;  // m = b*2048 + s
        const int col = bcol + wc + ni * 16 + l16;         // o = h*64 + hd
        const int bb = row >> 11, ss = row & 2047;
        const int hh = col >> 6, hd = col & 63;
        if (wsel == 2) {
          Vo[((size_t)(bb * 16 + hh) * 64 + hd) * 2048 + ss] = __float2bfloat16(v);
        } else {
          float other = __shfl_xor(v, 1);
          const int p = hd >> 1;
          const float c = fcos[ss * 32 + p];
          const float sn = fsin[ss * 32 + p];
          float r = (col & 1) ? (other * sn + v * c) : (v * c - other * sn);
          __hip_bfloat16* dst = (wsel == 0) ? Qo : Ko;
          if (wsel == 0) r *= QSCALE;
          dst[((size_t)(bb * 16 + hh) * 2048 + ss) * 64 + hd] = __float2bfloat16(r);
        }
      }
}

// ---------------- out-projection GEMM (64x128 tile) -> fp32 d_out ----------
__global__ __launch_bounds__(256) void gemm_out(
    const __hip_bfloat16* __restrict__ A,    // [4096][1024]
    const __hip_bfloat16* __restrict__ W,    // [1024][1024]
    float* __restrict__ C) {
  __shared__ __hip_bfloat16 sA[64 * 32];
  __shared__ __hip_bfloat16 sB[128 * 32];

  const int tid = threadIdx.x;
  const int wid = tid >> 6;
  const int lane = tid & 63;
  const int l4 = lane >> 4, l16 = lane & 15;
  const int brow = blockIdx.x * 64;
  const int bcol = blockIdx.y * 128;
  const int wr = (wid & 1) * 32;
  const int wc = (wid >> 1) * 64;

  f32x4 acc[2][4] = {};

  const __hip_bfloat16* Ap = A + (size_t)(brow + (tid >> 2)) * 1024 + (tid & 3) * 8;
  const __hip_bfloat16* Wp = W + (size_t)(bcol + (tid >> 2)) * 1024 + (tid & 3) * 8;
  char* sAc = (char*)sA + wid * 1024;
  char* sBc = (char*)sB + wid * 1024;

  for (int kt = 0; kt < 32; ++kt) {
    const int k0 = kt * 32;
    __syncthreads();
    gload_lds16(Ap + k0,             sAc);
    gload_lds16(Wp + k0,             sBc);
    gload_lds16(Wp + 64 * 1024 + k0, sBc + 4096);
    __syncthreads();

    bf16x8 af[2], bfr[4];
#pragma unroll
    for (int i = 0; i < 2; ++i)
      af[i] = *(const bf16x8*)&sA[(wr + i * 16 + l16) * 32 + l4 * 8];
#pragma unroll
    for (int i = 0; i < 4; ++i)
      bfr[i] = *(const bf16x8*)&sB[(wc + i * 16 + l16) * 32 + l4 * 8];
#pragma unroll
    for (int mi = 0; mi < 2; ++mi)
#pragma unroll
      for (int ni = 0; ni < 4; ++ni)
        acc[mi][ni] = mfma16(af[mi], bfr[ni], acc[mi][ni]);
  }

#pragma unroll
  for (int mi = 0; mi < 2; ++mi)
#pragma unroll
    for (int ni = 0; ni < 4; ++ni)
#pragma unroll
      for (int j = 0; j < 4; ++j) {
        const int row = brow + wr + mi * 16 + l4 * 4 + j;
        const int col = bcol + wc + ni * 16 + l16;
        C[(size_t)row * 1024 + col] = acc[mi][ni][j];
      }
}

// ---------------- flash attention (single-wave blocks, barrier-free) -------
// 2048 blocks x 64 threads. Block L -> q-group g = 63-(L>>5) (32 q-rows,
// heavy-first LPT order), head bh = L&31. K/V fragments direct from global
// (L1/L2-resident). Only the per-wave P tile lives in LDS. No barriers.
__global__ __launch_bounds__(64) void attn_fwd(
    const __hip_bfloat16* __restrict__ Q,   // [B,H,S,64] (pre-scaled, log2 dom)
    const __hip_bfloat16* __restrict__ K,   // [B,H,S,64]
    const __hip_bfloat16* __restrict__ VT,  // [B,H,64,S]
    __hip_bfloat16* __restrict__ AO) {      // [B,S,1024]
  const int L = blockIdx.x;
  const int g = 63 - (L >> 5);
  const int bh = L & 31;
  const int bb = bh >> 4;
  const int hh = bh & 15;
  const int lane = threadIdx.x & 63;
  const int l4 = lane >> 4, l16 = lane & 15;
  const int wq0 = g * 32;

  const __hip_bfloat16* Qg = Q + (size_t)bh * 2048 * 64;
  const __hip_bfloat16* Kg = K + (size_t)bh * 2048 * 64;
  const __hip_bfloat16* Vg = VT + (size_t)bh * 64 * 2048;

  __shared__ __hip_bfloat16 sP[32][72];   // per-wave P; no barriers needed

  // Q fragments (MFMA B-operand: q = l16, d contiguous)
  bf16x8 qf[2][2];
#pragma unroll
  for (int q2 = 0; q2 < 2; ++q2)
#pragma unroll
    for (int dk = 0; dk < 2; ++dk)
      qf[q2][dk] = *(const bf16x8*)&Qg[(size_t)(wq0 + q2 * 16 + l16) * 64 + dk * 32 + l4 * 8];

  float mrun[2] = {-1e30f, -1e30f};   // log2-domain running max for q = wq0+q2*16+l16
  float lrun[2] = {0.f, 0.f};
  f32x4 oacc[2][4] = {};              // O rows q=(l4,j), cols d=l16

  const int lastkv = (wq0 + 31) >> 6;
  for (int kv = 0; kv <= lastkv; ++kv) {
    const int kb = kv * 64;

    // K fragments direct from global (swapped-QK A-operand: k rows, d cols)
    bf16x8 kfr[4][2];
#pragma unroll
    for (int kf = 0; kf < 4; ++kf)
#pragma unroll
      for (int dk = 0; dk < 2; ++dk)
        kfr[kf][dk] = *(const bf16x8*)&Kg[(size_t)(kb + kf * 16 + l16) * 64 + dk * 32 + l4 * 8];

    // swapped QK^T: C[k=(l4,j)][q=l16]
    f32x4 sacc[4][2] = {};
    __builtin_amdgcn_s_setprio(1);
#pragma unroll
    for (int dk = 0; dk < 2; ++dk)
#pragma unroll
      for (int kf = 0; kf < 4; ++kf)
#pragma unroll
        for (int q2 = 0; q2 < 2; ++q2)
          sacc[kf][q2] = mfma16(kfr[kf][dk], qf[q2][dk], sacc[kf][q2]);
    __builtin_amdgcn_s_setprio(0);

    // V fragments issued now; latency hides under softmax VALU work
    bf16x8 vfr[4][2];
#pragma unroll
    for (int df = 0; df < 4; ++df)
#pragma unroll
      for (int ks = 0; ks < 2; ++ks)
        vfr[df][ks] = *(const bf16x8*)&Vg[(size_t)(df * 16 + l16) * 2048 + kb + ks * 32 + l4 * 8];

    const bool need_mask = (kb + 63 > wq0);  // only the diagonal tile
    float fac[2];
#pragma unroll
    for (int q2 = 0; q2 < 2; ++q2) {
      const int qi = wq0 + q2 * 16 + l16;
      float pv[16];
#pragma unroll
      for (int kf = 0; kf < 4; ++kf)
#pragma unroll
        for (int j = 0; j < 4; ++j) {
          float s = sacc[kf][q2][j];
          if (need_mask && (kb + kf * 16 + l4 * 4 + j > qi)) s = -1e30f;
          pv[kf * 4 + j] = s;
        }
      float m0 = fmaxf(fmaxf(pv[0], pv[1]), fmaxf(pv[2], pv[3]));
      float m1 = fmaxf(fmaxf(pv[4], pv[5]), fmaxf(pv[6], pv[7]));
      float m2 = fmaxf(fmaxf(pv[8], pv[9]), fmaxf(pv[10], pv[11]));
      float m3 = fmaxf(fmaxf(pv[12], pv[13]), fmaxf(pv[14], pv[15]));
      float mloc = fmaxf(fmaxf(m0, m1), fmaxf(m2, m3));
      mloc = fmaxf(mloc, __shfl_xor(mloc, 16));
      mloc = fmaxf(mloc, __shfl_xor(mloc, 32));
      const float mold = mrun[q2];
      const float mnew = fmaxf(mold, mloc);
      const float f = exp2f(mold - mnew);
      fac[q2] = f;
      mrun[q2] = mnew;
      float ts = 0.f;
      float pe[16];
#pragma unroll
      for (int t = 0; t < 16; ++t) { pe[t] = exp2f(pv[t] - mnew); ts += pe[t]; }
#pragma unroll
      for (int kf = 0; kf < 4; ++kf) {
        uint2 w;
        w.x = pkbf2(pe[kf * 4 + 0], pe[kf * 4 + 1]);
        w.y = pkbf2(pe[kf * 4 + 2], pe[kf * 4 + 3]);
        *(uint2*)&sP[q2 * 16 + l16][kf * 16 + l4 * 4] = w;
      }
      ts += __shfl_xor(ts, 16);
      ts += __shfl_xor(ts, 32);
      lrun[q2] = lrun[q2] * f + ts;
    }

    // rescale O: row q=(l4,j) needs fac from lane l16 = l4*4+j
#pragma unroll
    for (int mf = 0; mf < 2; ++mf)
#pragma unroll
      for (int j = 0; j < 4; ++j) {
        const float fr = __shfl(fac[mf], l4 * 4 + j);
#pragma unroll
        for (int df = 0; df < 4; ++df) oacc[mf][df][j] *= fr;
      }

    // O += P V  (P from per-wave LDS; V fragments already in flight)
    __builtin_amdgcn_s_setprio(1);
#pragma unroll
    for (int ks = 0; ks < 2; ++ks) {
      bf16x8 pfr[2];
#pragma unroll
      for (int mf = 0; mf < 2; ++mf)
        pfr[mf] = *(const bf16x8*)&sP[mf * 16 + l16][ks * 32 + l4 * 8];
#pragma unroll
      for (int mf = 0; mf < 2; ++mf)
#pragma unroll
        for (int df = 0; df < 4; ++df)
          oacc[mf][df] = mfma16(pfr[mf], vfr[df][ks], oacc[mf][df]);
    }
    __builtin_amdgcn_s_setprio(0);
  }

  // normalize and store [B,S,H*64+hd] bf16
  float inv[2];
#pragma unroll
  for (int q2 = 0; q2 < 2; ++q2) inv[q2] = 1.f / lrun[q2];
#pragma unroll
  for (int mf = 0; mf < 2; ++mf)
#pragma unroll
    for (int j = 0; j < 4; ++j) {
      const float ir = __shfl(inv[mf], l4 * 4 + j);
      const int ss = wq0 + mf * 16 + l4 * 4 + j;
#pragma unroll
      for (int df = 0; df < 4; ++df) {
        const int dd = hh * 64 + df * 16 + l16;
        AO[((size_t)bb * 2048 + ss) * 1024 + dd] =
            __float2bfloat16(oacc[mf][df][j] * ir);
      }
    }
}

// ---------------- launch ----------------
extern "C" void kernel_launch(void* const* d_in, const int* in_sizes, int n_in,
                              void* d_out, int out_size, void* d_ws, size_t ws_size,
                              hipStream_t stream) {
  const float* x  = (const float*)d_in[0];
  const float* wq = (const float*)d_in[1];
  const float* wk = (const float*)d_in[2];
  const float* wv = (const float*)d_in[3];
  const float* wo = (const float*)d_in[4];
  const float* fc = (const float*)d_in[5];
  const float* fs = (const float*)d_in[6];

  char* ws = (char*)d_ws;
  const size_t MB = 1024 * 1024;
  __hip_bfloat16* xb  = (__hip_bfloat16*)(ws);              // 8 MB
  __hip_bfloat16* wqb = (__hip_bfloat16*)(ws + 8 * MB);     // 2 MB each
  __hip_bfloat16* wkb = (__hip_bfloat16*)(ws + 10 * MB);
  __hip_bfloat16* wvb = (__hip_bfloat16*)(ws + 12 * MB);
  __hip_bfloat16* wob = (__hip_bfloat16*)(ws + 14 * MB);
  __hip_bfloat16* qws = (__hip_bfloat16*)(ws + 16 * MB);    // [B,H,S,64]
  __hip_bfloat16* kws = (__hip_bfloat16*)(ws + 24 * MB);
  __hip_bfloat16* vws = (__hip_bfloat16*)(ws + 32 * MB);    // [B,H,64,S]
  __hip_bfloat16* ao  = (__hip_bfloat16*)(ws + 40 * MB);    // [B,S,1024]

  cvt_bf16<<<2048, 256, 0, stream>>>(x, xb, NM * ND / 4);
  cvt_w4<<<4096, 256, 0, stream>>>(wq, wk, wv, wo, wqb, wkb, wvb, wob);

  gemm_qkv<<<dim3(NM / 128, 24), 256, 0, stream>>>(xb, wqb, wkb, wvb, fc, fs,
                                                   qws, kws, vws);

  attn_fwd<<<dim3(2048), 64, 0, stream>>>(qws, kws, vws, ao);

  gemm_out<<<dim3(NM / 64, ND / 128), 256, 0, stream>>>(ao, wob, (float*)d_out);
}